// Round 21
// baseline (114.613 us; speedup 1.0000x reference)
//
#include <hip/hip_runtime.h>
#include <hip/hip_bf16.h>
#include <stdint.h>

typedef __attribute__((ext_vector_type(8))) __bf16 bf16x8;
typedef __attribute__((ext_vector_type(4))) __bf16 bf16x4;
typedef __attribute__((ext_vector_type(2))) __bf16 bf16x2;
typedef __attribute__((ext_vector_type(4))) float f32x4;
typedef __attribute__((ext_vector_type(4))) unsigned int u32x4;

#define MFMA16(a,b,c) __builtin_amdgcn_mfma_f32_16x16x32_bf16((a),(b),(c),0,0,0)

#define BATCH 8
#define NPTS  2048
#define GRID  (BATCH * NPTS / 2)   // 2 bn per block

// ---- swizzles ----
__device__ __forceinline__ int swz128(int row, int col) {      // 64-col bf16 rows
    return row*128 + ((col*2) ^ (((row + (row >> 3)) & 7) << 4));
}
__device__ __forceinline__ int swz64(int row, int col) {       // 32-col bf16 rows
    return row*64 + ((col*2) ^ (((row + (row >> 2)) & 3) << 4));
}
__device__ __forceinline__ __bf16* p128(char* base, int row, int col) {
    return (__bf16*)(base + swz128(row, col));
}
__device__ __forceinline__ bf16x8 ld8_128(char* base, int row, int col) {
    return *(const bf16x8*)p128(base, row, col);
}
__device__ __forceinline__ bf16x8 ld8_64(char* base, int row, int col) {
    return *(const bf16x8*)(base + swz64(row, col));
}
// pack two f32 -> one u32 of 2 bf16
__device__ __forceinline__ unsigned packbf(float lo, float hi) {
    bf16x2 v; v[0] = (__bf16)lo; v[1] = (__bf16)hi;
    return __builtin_bit_cast(unsigned, v);
}
__device__ __forceinline__ bf16x8 fragw(unsigned w0, unsigned w1,
                                        unsigned w2, unsigned w3) {
    u32x4 v; v[0] = w0; v[1] = w1; v[2] = w2; v[3] = w3;
    return __builtin_bit_cast(bf16x8, v);
}

// ---- pre-pass: fused weight image in d_ws -----------------------------------
// bytes: [0,8192)     Wo^T [n=64][k=64] swz128
//        [8192,12288) W2^T [f=64][db=32 pad] swz64, W2 = Wv@Wo (EXACT 0 db>=16)
//        [12288,14336) M^T [db=16][d=64] linear, M = SCALE*Wq@Wk^T
__global__ void prep_weights(const float* __restrict__ Wq, const float* __restrict__ Wk,
                             const float* __restrict__ Wv, const float* __restrict__ Wo,
                             __bf16* __restrict__ ws)
{
    int idx = blockIdx.x * 256 + threadIdx.x;   // 0..7167
    char* wsb = (char*)ws;
    if (idx < 4096) {
        int n = idx >> 6, k = idx & 63;
        *(__bf16*)(wsb + swz128(n, k)) = (__bf16)Wo[k*64 + n];
    } else if (idx < 6144) {
        int i = idx - 4096, f = i >> 5, db = i & 31;
        float acc = 0.f;
        if (db < 16) {
            for (int e = 0; e < 64; ++e) acc += Wv[db*64 + e] * Wo[e*64 + f];
        }
        *(__bf16*)(wsb + 8192 + swz64(f, db)) = (__bf16)acc;
    } else if (idx < 7168) {
        int i = idx - 6144, db = i >> 6, d = i & 63;
        float acc = 0.f;
        for (int e = 0; e < 64; ++e) acc += Wq[d*64 + e] * Wk[db*64 + e];
        *(__bf16*)(wsb + 12288 + db*128 + d*2) = (__bf16)(acc * 0.125f);
    }
}

__global__ void __launch_bounds__(256, 5) xattn_kernel(
    const float* __restrict__ voxel, const float* __restrict__ trans,
    const float* __restrict__ ws,     // prebuilt weight image (14 KB)
    const float* __restrict__ bo, const float* __restrict__ lng,
    const float* __restrict__ lnb, float* __restrict__ out)
{
    // LDS 32768 B -> 5 blocks/CU (163840 = 160 KiB exactly). Phase 1:
    // [0,8192) Wot | [8192,12288) W2t | [12288,28672) Xb[2]   (no XPb: shuffles)
    // Phase 2 (after barrier 2, arena dead): Ybuf[2] = [64][64] f32 x2 = 32768 B.
    __shared__ __align__(16) char lds[32768];
    char* Wot = lds;
    char* W2t = lds + 8192;
    #define XBQ(q)  (lds + 12288 + (q)*8192)

    const int tid = threadIdx.x;
    const int bn0 = blockIdx.x * 2;
    const int w   = tid >> 6;     // wave 0..3; wave owns rows 16w..16w+15
    const int l   = tid & 63;
    const int l15 = l & 15;
    const int lq  = l >> 4;       // 0..3

    const f32x4 fzero = {0.f, 0.f, 0.f, 0.f};
    // shuffle source lanes for the k-redistribution (same l15 column group):
    // element i of a row-k fragment (k=lq*8+i) lives at lane l15+16*((2lq+(i>=4))&3)
    const int srcA = l15 + 16*(( 2*lq     ) & 3);   // words m=0,1 (i<4)
    const int srcB = l15 + 16*(( 2*lq + 1 ) & 3);   // words m=2,3 (i>=4)
    const bool act = (lq < 2);                      // real k<16 lanes

    // ---------------- stage (both tasks) -------------------------------------
    bf16x8 mf0, mf1, tfrag0[2], tfrag1[2], ttf0, ttf1;
    {
        const char* wsb = (const char*)ws;
        // REG-STAGED weight image copy (12 KB = 3 sweeps of 4 KB).
        u32x4 wimg[3];
        #pragma unroll
        for (int i = 0; i < 3; ++i)
            wimg[i] = *(const u32x4*)(wsb + i*4096 + tid*16);
        #pragma unroll
        for (int i = 0; i < 3; ++i)
            *(u32x4*)(lds + i*4096 + tid*16) = wimg[i];
        // M^T fragments: lane holds M^T[db=l15][k=d] (A of transposed XM)
        mf0 = *(const bf16x8*)(wsb + 12288 + l15*128 + lq*16);
        mf1 = *(const bf16x8*)(wsb + 12288 + l15*128 + 64 + lq*16);
        #pragma unroll
        for (int q = 0; q < 2; ++q) {
            const int bn = bn0 + q;
            bf16x8* tf = (q == 0) ? tfrag0 : tfrag1;
            // T row fragments: lane holds T[j=16tj+l15][k=db] (A of transposed S)
            #pragma unroll
            for (int i = 0; i < 8; ++i) { tf[0][i] = (__bf16)0.f; tf[1][i] = (__bf16)0.f; }
            if (lq < 2) {
                #pragma unroll
                for (int tj = 0; tj < 2; ++tj) {
                    const f32x4* gT = (const f32x4*)(trans + (size_t)bn*512 + (16*tj + l15)*16 + lq*8);
                    f32x4 u0 = gT[0], u1 = gT[1];
                    #pragma unroll
                    for (int i = 0; i < 4; ++i) {
                        tf[tj][i]     = (__bf16)u0[i];
                        tf[tj][i + 4] = (__bf16)u1[i];
                    }
                }
            }
            // T^T fragment: lane holds T^T[db=l15][k=j] (A of transposed PT)
            {
                const float* gT = trans + (size_t)bn * 512;
                float tt[8];
                #pragma unroll
                for (int i = 0; i < 8; ++i) tt[i] = gT[(lq*8 + i)*16 + l15];
                bf16x8 tv;
                #pragma unroll
                for (int i = 0; i < 8; ++i) tv[i] = (__bf16)tt[i];
                if (q == 0) ttf0 = tv; else ttf1 = tv;
            }
            // X: [64][64] f32 coalesced -> Xb bf16 swz128
            const f32x4* gX = (const f32x4*)(voxel + (size_t)bn * 4096);
            #pragma unroll
            for (int j = 0; j < 4; ++j) {
                f32x4 v = gX[j*256 + tid];
                int gi  = j*256 + tid;
                int row = gi >> 4;
                int col = (gi & 15) * 4;
                bf16x4 h;
                #pragma unroll
                for (int i = 0; i < 4; ++i) h[i] = (__bf16)v[i];
                *(bf16x4*)p128(XBQ(q), row, col) = h;
            }
        }
    }
    // explicit drain (r10 post-mortem)
    asm volatile("s_waitcnt vmcnt(0) lgkmcnt(0)" ::: "memory");
    __syncthreads();   // barrier 1.

    bf16x8 xa00 = ld8_128(XBQ(0), 16*w + l15, lq*8);
    bf16x8 xa01 = ld8_128(XBQ(0), 16*w + l15, 32 + lq*8);
    bf16x8 xa10 = ld8_128(XBQ(1), 16*w + l15, lq*8);
    bf16x8 xa11 = ld8_128(XBQ(1), 16*w + l15, 32 + lq*8);

    // ------ XM^T = M^T @ X^T: lane holds XM[16w+l15][db=lq*4+r] --------------
    // Redistribute to row-k fragments via shuffles (no LDS round-trip).
    // Lanes lq>=2 receive finite garbage; downstream tfrag zeros kill it.
    bf16x8 xma0, xma1;
    {
        f32x4 xm0 = MFMA16(mf0, xa00, fzero);
        xm0 = MFMA16(mf1, xa01, xm0);
        f32x4 xm1 = MFMA16(mf0, xa10, fzero);
        xm1 = MFMA16(mf1, xa11, xm1);
        unsigned a0 = packbf(xm0[0], xm0[1]), a1 = packbf(xm0[2], xm0[3]);
        unsigned b0 = packbf(xm1[0], xm1[1]), b1 = packbf(xm1[2], xm1[3]);
        xma0 = fragw(__shfl(a0, srcA), __shfl(a1, srcA),
                     __shfl(a0, srcB), __shfl(a1, srcB));
        xma1 = fragw(__shfl(b0, srcA), __shfl(b1, srcA),
                     __shfl(b0, srcB), __shfl(b1, srcB));
    }
    // ------ S^T = T @ XM^T: lane holds S[16w+l15][j=16tj+lq*4+r] -------------
    // softmax row-sum: 8 in-lane + 2 shuffles; then P -> row-j fragments (ap)
    bf16x8 ap0, ap1;
    {
        f32x4 sa0 = MFMA16(tfrag0[0], xma0, fzero);
        f32x4 sa1 = MFMA16(tfrag0[1], xma0, fzero);
        f32x4 sb0 = MFMA16(tfrag1[0], xma1, fzero);
        f32x4 sb1 = MFMA16(tfrag1[1], xma1, fzero);
        float pa0[4], pa1[4], pb0[4], pb1[4];
        float sua = 0.f, sub = 0.f;
        #pragma unroll
        for (int r = 0; r < 4; ++r) {
            pa0[r] = __expf(sa0[r]); pa1[r] = __expf(sa1[r]);
            pb0[r] = __expf(sb0[r]); pb1[r] = __expf(sb1[r]);
            sua += pa0[r] + pa1[r];
            sub += pb0[r] + pb1[r];
        }
        sua += __shfl_xor(sua, 16); sub += __shfl_xor(sub, 16);
        sua += __shfl_xor(sua, 32); sub += __shfl_xor(sub, 32);
        float inva = __builtin_amdgcn_rcpf(sua);
        float invb = __builtin_amdgcn_rcpf(sub);
        unsigned a00 = packbf(pa0[0]*inva, pa0[1]*inva);
        unsigned a01 = packbf(pa0[2]*inva, pa0[3]*inva);
        unsigned a10 = packbf(pa1[0]*inva, pa1[1]*inva);
        unsigned a11 = packbf(pa1[2]*inva, pa1[3]*inva);
        unsigned b00 = packbf(pb0[0]*invb, pb0[1]*invb);
        unsigned b01 = packbf(pb0[2]*invb, pb0[3]*invb);
        unsigned b10 = packbf(pb1[0]*invb, pb1[1]*invb);
        unsigned b11 = packbf(pb1[2]*invb, pb1[3]*invb);
        // ap word m: j=lq*8 span; lanes lq<2 read tj=0 (p0), lq>=2 tj=1 (p1)
        unsigned s0, s1, s2, s3, t0, t1, t2, t3;
        s0 = __shfl(a00, srcA); s1 = __shfl(a01, srcA);
        s2 = __shfl(a00, srcB); s3 = __shfl(a01, srcB);
        t0 = __shfl(a10, srcA); t1 = __shfl(a11, srcA);
        t2 = __shfl(a10, srcB); t3 = __shfl(a11, srcB);
        ap0 = fragw(act ? s0 : t0, act ? s1 : t1, act ? s2 : t2, act ? s3 : t3);
        s0 = __shfl(b00, srcA); s1 = __shfl(b01, srcA);
        s2 = __shfl(b00, srcB); s3 = __shfl(b01, srcB);
        t0 = __shfl(b10, srcA); t1 = __shfl(b11, srcA);
        t2 = __shfl(b10, srcB); t3 = __shfl(b11, srcB);
        ap1 = fragw(act ? s0 : t0, act ? s1 : t1, act ? s2 : t2, act ? s3 : t3);
    }
    // ------ PT^T = T^T @ P^T: lane holds PT[16w+l15][db=lq*4+r] --------------
    // -> row-k fragments (pta); k>=16 garbage killed by W2t exact zeros.
    bf16x8 pta0, pta1;
    {
        f32x4 pt0 = MFMA16(ttf0, ap0, fzero);
        f32x4 pt1 = MFMA16(ttf1, ap1, fzero);
        unsigned a0 = packbf(pt0[0], pt0[1]), a1 = packbf(pt0[2], pt0[3]);
        unsigned b0 = packbf(pt1[0], pt1[1]), b1 = packbf(pt1[2], pt1[3]);
        pta0 = fragw(__shfl(a0, srcA), __shfl(a1, srcA),
                     __shfl(a0, srcB), __shfl(a1, srcB));
        pta1 = fragw(__shfl(b0, srcA), __shfl(b1, srcA),
                     __shfl(b0, srcB), __shfl(b1, srcB));
    }
    // ---------------- epilogue MFMAs: Y = PT@W2 + X@Wo (classic orient.) -----
    f32x4 y0[4], y1[4];
    {
        #pragma unroll
        for (int t = 0; t < 4; ++t) {
            bf16x8 b0  = ld8_128(Wot, 16*t + l15, lq*8);
            bf16x8 b1  = ld8_128(Wot, 16*t + l15, 32 + lq*8);
            bf16x8 w2b = ld8_64 (W2t, 16*t + l15, lq*8);
            y0[t] = MFMA16(xa00, b0, fzero);
            y0[t] = MFMA16(xa01, b1, y0[t]);
            y0[t] = MFMA16(pta0, w2b, y0[t]);
            y1[t] = MFMA16(xa10, b0, fzero);
            y1[t] = MFMA16(xa11, b1, y1[t]);
            y1[t] = MFMA16(pta1, w2b, y1[t]);
        }
    }
    __syncthreads();   // barrier 2: ALL waves' LDS reads done -> arena is dead.
    // ---------------- + bo; LayerNorm; LDS-transpose; coalesced NT store -----
    // Ybuf stride 64 (no pad): 2x16384 = 32768 B fits exactly; the 4-way bank
    // aliasing on the scalar LN writes costs ~1.6x on 32 ops/thread -- trivial
    // against the occupancy gain (4 -> 5 blocks/CU).
    {
        float bo4[4], g4[4], b4[4];
        #pragma unroll
        for (int t = 0; t < 4; ++t) {
            int c = 16*t + l15;
            bo4[t] = bo[c]; g4[t] = lng[c]; b4[t] = lnb[c];
        }
        #pragma unroll
        for (int q = 0; q < 2; ++q) {
            float* Ybuf = (float*)(lds + q*16384);   // [64][64] f32, intra-wave rows
            #pragma unroll
            for (int r = 0; r < 4; ++r) {
                float v0 = ((q == 0) ? y0[0][r] : y1[0][r]) + bo4[0];
                float v1 = ((q == 0) ? y0[1][r] : y1[1][r]) + bo4[1];
                float v2 = ((q == 0) ? y0[2][r] : y1[2][r]) + bo4[2];
                float v3 = ((q == 0) ? y0[3][r] : y1[3][r]) + bo4[3];
                float s1 = v0 + v1 + v2 + v3;
                float s2 = v0*v0 + v1*v1 + v2*v2 + v3*v3;
                #pragma unroll
                for (int off = 1; off < 16; off <<= 1) {
                    s1 += __shfl_xor(s1, off);
                    s2 += __shfl_xor(s2, off);
                }
                float mu  = s1 * 0.015625f;
                float var = s2 * 0.015625f - mu * mu;
                float rs  = rsqrtf(var + 1e-5f);
                float* yrow = Ybuf + (16*w + lq*4 + r) * 64;
                yrow[     l15] = (v0 - mu) * rs * g4[0] + b4[0];
                yrow[16 + l15] = (v1 - mu) * rs * g4[1] + b4[1];
                yrow[32 + l15] = (v2 - mu) * rs * g4[2] + b4[2];
                yrow[48 + l15] = (v3 - mu) * rs * g4[3] + b4[3];
            }
            // read back row-major; 4 fully-contiguous 1 KB wave NT stores
            float* gout = out + (size_t)(bn0 + q) * 4096;
            #pragma unroll
            for (int s = 0; s < 4; ++s) {
                int row = 16*w + 4*s + (l >> 4);
                f32x4 v = *(const f32x4*)(Ybuf + row*64 + (l & 15)*4);
                __builtin_nontemporal_store(v, (f32x4*)(gout + row*64 + (l & 15)*4));
            }
        }
    }
    #undef XBQ
}

extern "C" void kernel_launch(void* const* d_in, const int* in_sizes, int n_in,
                              void* d_out, int out_size, void* d_ws, size_t ws_size,
                              hipStream_t stream) {
    const float* voxel = (const float*)d_in[0];
    const float* trans = (const float*)d_in[1];
    const float* Wq = (const float*)d_in[2];
    const float* Wk = (const float*)d_in[3];
    const float* Wv = (const float*)d_in[4];
    const float* Wo = (const float*)d_in[5];
    const float* bo = (const float*)d_in[6];
    const float* g  = (const float*)d_in[7];
    const float* b  = (const float*)d_in[8];
    float* o = (float*)d_out;

    prep_weights<<<dim3(28), dim3(256), 0, stream>>>(Wq, Wk, Wv, Wo, (__bf16*)d_ws);
    xattn_kernel<<<dim3(GRID), dim3(256), 0, stream>>>(
        voxel, trans, (const float*)d_ws, bo, g, b, o);
}

// Round 22
// 111.274 us; speedup vs baseline: 1.0300x; 1.0300x over previous
//
#include <hip/hip_runtime.h>
#include <hip/hip_bf16.h>
#include <stdint.h>

typedef __attribute__((ext_vector_type(8))) __bf16 bf16x8;
typedef __attribute__((ext_vector_type(4))) __bf16 bf16x4;
typedef __attribute__((ext_vector_type(2))) __bf16 bf16x2;
typedef __attribute__((ext_vector_type(4))) float f32x4;
typedef __attribute__((ext_vector_type(4))) unsigned int u32x4;

#define MFMA16(a,b,c) __builtin_amdgcn_mfma_f32_16x16x32_bf16((a),(b),(c),0,0,0)

#define BATCH 8
#define NPTS  2048
#define GRID  (BATCH * NPTS / 2)   // 2 bn per block

// ---- swizzles ----
__device__ __forceinline__ int swz128(int row, int col) {      // 64-col bf16 rows
    return row*128 + ((col*2) ^ (((row + (row >> 3)) & 7) << 4));
}
__device__ __forceinline__ int swz64(int row, int col) {       // 32-col bf16 rows
    return row*64 + ((col*2) ^ (((row + (row >> 2)) & 3) << 4));
}
__device__ __forceinline__ __bf16* p128(char* base, int row, int col) {
    return (__bf16*)(base + swz128(row, col));
}
__device__ __forceinline__ bf16x8 ld8_128(char* base, int row, int col) {
    return *(const bf16x8*)p128(base, row, col);
}
__device__ __forceinline__ bf16x8 ld8_64(char* base, int row, int col) {
    return *(const bf16x8*)(base + swz64(row, col));
}
// pack two f32 -> one u32 of 2 bf16
__device__ __forceinline__ unsigned packbf(float lo, float hi) {
    bf16x2 v; v[0] = (__bf16)lo; v[1] = (__bf16)hi;
    return __builtin_bit_cast(unsigned, v);
}
__device__ __forceinline__ bf16x8 fragw(unsigned w0, unsigned w1,
                                        unsigned w2, unsigned w3) {
    u32x4 v; v[0] = w0; v[1] = w1; v[2] = w2; v[3] = w3;
    return __builtin_bit_cast(bf16x8, v);
}

// ---- pre-pass: fused weight image in d_ws -----------------------------------
// bytes: [0,8192)     Wo^T [n=64][k=64] swz128
//        [8192,12288) W2^T [f=64][db=32 pad] swz64, W2 = Wv@Wo (EXACT 0 db>=16)
//        [12288,14336) M^T [db=16][d=64] linear, M = SCALE*Wq@Wk^T
__global__ void prep_weights(const float* __restrict__ Wq, const float* __restrict__ Wk,
                             const float* __restrict__ Wv, const float* __restrict__ Wo,
                             __bf16* __restrict__ ws)
{
    int idx = blockIdx.x * 256 + threadIdx.x;   // 0..7167
    char* wsb = (char*)ws;
    if (idx < 4096) {
        int n = idx >> 6, k = idx & 63;
        *(__bf16*)(wsb + swz128(n, k)) = (__bf16)Wo[k*64 + n];
    } else if (idx < 6144) {
        int i = idx - 4096, f = i >> 5, db = i & 31;
        float acc = 0.f;
        if (db < 16) {
            for (int e = 0; e < 64; ++e) acc += Wv[db*64 + e] * Wo[e*64 + f];
        }
        *(__bf16*)(wsb + 8192 + swz64(f, db)) = (__bf16)acc;
    } else if (idx < 7168) {
        int i = idx - 6144, db = i >> 6, d = i & 63;
        float acc = 0.f;
        for (int e = 0; e < 64; ++e) acc += Wq[d*64 + e] * Wk[db*64 + e];
        *(__bf16*)(wsb + 12288 + db*128 + d*2) = (__bf16)(acc * 0.125f);
    }
}

__global__ void __launch_bounds__(256, 5) xattn_kernel(
    const float* __restrict__ voxel, const float* __restrict__ trans,
    const float* __restrict__ ws,     // prebuilt weight image (14 KB)
    const float* __restrict__ bo, const float* __restrict__ lng,
    const float* __restrict__ lnb, float* __restrict__ out)
{
    // LDS 28672 B -> 5 blocks/CU (143360 <= 163840, 20 KB slack for reserve).
    // Phase 1: [0,8192) Wot | [8192,12288) W2t | [12288,28672) Xb[2]
    // Phase 2 (after barrier 2, arena dead): ONE shared Ybuf [64][64] f32
    // = 16384 B at lds+0, reused sequentially by q=0 then q=1 (rows are
    // wave-private; same-wave LDS write->read FIFO orders the reuse).
    __shared__ __align__(16) char lds[28672];
    char* Wot = lds;
    char* W2t = lds + 8192;
    #define XBQ(q)  (lds + 12288 + (q)*8192)

    const int tid = threadIdx.x;
    const int bn0 = blockIdx.x * 2;
    const int w   = tid >> 6;     // wave 0..3; wave owns rows 16w..16w+15
    const int l   = tid & 63;
    const int l15 = l & 15;
    const int lq  = l >> 4;       // 0..3

    const f32x4 fzero = {0.f, 0.f, 0.f, 0.f};
    // shuffle source lanes for the k-redistribution (same l15 column group):
    // element i of a row-k fragment (k=lq*8+i) lives at lane l15+16*((2lq+(i>=4))&3)
    const int srcA = l15 + 16*(( 2*lq     ) & 3);   // words m=0,1 (i<4)
    const int srcB = l15 + 16*(( 2*lq + 1 ) & 3);   // words m=2,3 (i>=4)
    const bool act = (lq < 2);                      // real k<16 lanes

    // ---------------- stage (both tasks) -------------------------------------
    bf16x8 mf0, mf1, tfrag0[2], tfrag1[2], ttf0, ttf1;
    {
        const char* wsb = (const char*)ws;
        // REG-STAGED weight image copy (12 KB = 3 sweeps of 4 KB).
        u32x4 wimg[3];
        #pragma unroll
        for (int i = 0; i < 3; ++i)
            wimg[i] = *(const u32x4*)(wsb + i*4096 + tid*16);
        #pragma unroll
        for (int i = 0; i < 3; ++i)
            *(u32x4*)(lds + i*4096 + tid*16) = wimg[i];
        // M^T fragments: lane holds M^T[db=l15][k=d] (A of transposed XM)
        mf0 = *(const bf16x8*)(wsb + 12288 + l15*128 + lq*16);
        mf1 = *(const bf16x8*)(wsb + 12288 + l15*128 + 64 + lq*16);
        #pragma unroll
        for (int q = 0; q < 2; ++q) {
            const int bn = bn0 + q;
            bf16x8* tf = (q == 0) ? tfrag0 : tfrag1;
            // T row fragments: lane holds T[j=16tj+l15][k=db] (A of transposed S)
            #pragma unroll
            for (int i = 0; i < 8; ++i) { tf[0][i] = (__bf16)0.f; tf[1][i] = (__bf16)0.f; }
            if (lq < 2) {
                #pragma unroll
                for (int tj = 0; tj < 2; ++tj) {
                    const f32x4* gT = (const f32x4*)(trans + (size_t)bn*512 + (16*tj + l15)*16 + lq*8);
                    f32x4 u0 = gT[0], u1 = gT[1];
                    #pragma unroll
                    for (int i = 0; i < 4; ++i) {
                        tf[tj][i]     = (__bf16)u0[i];
                        tf[tj][i + 4] = (__bf16)u1[i];
                    }
                }
            }
            // T^T fragment: lane holds T^T[db=l15][k=j] (A of transposed PT)
            {
                const float* gT = trans + (size_t)bn * 512;
                float tt[8];
                #pragma unroll
                for (int i = 0; i < 8; ++i) tt[i] = gT[(lq*8 + i)*16 + l15];
                bf16x8 tv;
                #pragma unroll
                for (int i = 0; i < 8; ++i) tv[i] = (__bf16)tt[i];
                if (q == 0) ttf0 = tv; else ttf1 = tv;
            }
            // X: [64][64] f32 coalesced -> Xb bf16 swz128
            const f32x4* gX = (const f32x4*)(voxel + (size_t)bn * 4096);
            #pragma unroll
            for (int j = 0; j < 4; ++j) {
                f32x4 v = gX[j*256 + tid];
                int gi  = j*256 + tid;
                int row = gi >> 4;
                int col = (gi & 15) * 4;
                bf16x4 h;
                #pragma unroll
                for (int i = 0; i < 4; ++i) h[i] = (__bf16)v[i];
                *(bf16x4*)p128(XBQ(q), row, col) = h;
            }
        }
    }
    // explicit drain (r10 post-mortem)
    asm volatile("s_waitcnt vmcnt(0) lgkmcnt(0)" ::: "memory");
    __syncthreads();   // barrier 1.

    bf16x8 xa00 = ld8_128(XBQ(0), 16*w + l15, lq*8);
    bf16x8 xa01 = ld8_128(XBQ(0), 16*w + l15, 32 + lq*8);
    bf16x8 xa10 = ld8_128(XBQ(1), 16*w + l15, lq*8);
    bf16x8 xa11 = ld8_128(XBQ(1), 16*w + l15, 32 + lq*8);

    // ------ XM^T = M^T @ X^T: lane holds XM[16w+l15][db=lq*4+r] --------------
    // Redistribute to row-k fragments via shuffles (no LDS round-trip).
    // Lanes lq>=2 receive finite garbage; downstream tfrag zeros kill it.
    bf16x8 xma0, xma1;
    {
        f32x4 xm0 = MFMA16(mf0, xa00, fzero);
        xm0 = MFMA16(mf1, xa01, xm0);
        f32x4 xm1 = MFMA16(mf0, xa10, fzero);
        xm1 = MFMA16(mf1, xa11, xm1);
        unsigned a0 = packbf(xm0[0], xm0[1]), a1 = packbf(xm0[2], xm0[3]);
        unsigned b0 = packbf(xm1[0], xm1[1]), b1 = packbf(xm1[2], xm1[3]);
        xma0 = fragw(__shfl(a0, srcA), __shfl(a1, srcA),
                     __shfl(a0, srcB), __shfl(a1, srcB));
        xma1 = fragw(__shfl(b0, srcA), __shfl(b1, srcA),
                     __shfl(b0, srcB), __shfl(b1, srcB));
    }
    // ------ S^T = T @ XM^T: lane holds S[16w+l15][j=16tj+lq*4+r] -------------
    // softmax row-sum: 8 in-lane + 2 shuffles; then P -> row-j fragments (ap)
    bf16x8 ap0, ap1;
    {
        f32x4 sa0 = MFMA16(tfrag0[0], xma0, fzero);
        f32x4 sa1 = MFMA16(tfrag0[1], xma0, fzero);
        f32x4 sb0 = MFMA16(tfrag1[0], xma1, fzero);
        f32x4 sb1 = MFMA16(tfrag1[1], xma1, fzero);
        float pa0[4], pa1[4], pb0[4], pb1[4];
        float sua = 0.f, sub = 0.f;
        #pragma unroll
        for (int r = 0; r < 4; ++r) {
            pa0[r] = __expf(sa0[r]); pa1[r] = __expf(sa1[r]);
            pb0[r] = __expf(sb0[r]); pb1[r] = __expf(sb1[r]);
            sua += pa0[r] + pa1[r];
            sub += pb0[r] + pb1[r];
        }
        sua += __shfl_xor(sua, 16); sub += __shfl_xor(sub, 16);
        sua += __shfl_xor(sua, 32); sub += __shfl_xor(sub, 32);
        float inva = __builtin_amdgcn_rcpf(sua);
        float invb = __builtin_amdgcn_rcpf(sub);
        unsigned a00 = packbf(pa0[0]*inva, pa0[1]*inva);
        unsigned a01 = packbf(pa0[2]*inva, pa0[3]*inva);
        unsigned a10 = packbf(pa1[0]*inva, pa1[1]*inva);
        unsigned a11 = packbf(pa1[2]*inva, pa1[3]*inva);
        unsigned b00 = packbf(pb0[0]*invb, pb0[1]*invb);
        unsigned b01 = packbf(pb0[2]*invb, pb0[3]*invb);
        unsigned b10 = packbf(pb1[0]*invb, pb1[1]*invb);
        unsigned b11 = packbf(pb1[2]*invb, pb1[3]*invb);
        // ap word m: j=lq*8 span; lanes lq<2 read tj=0 (p0), lq>=2 tj=1 (p1)
        unsigned s0, s1, s2, s3, t0, t1, t2, t3;
        s0 = __shfl(a00, srcA); s1 = __shfl(a01, srcA);
        s2 = __shfl(a00, srcB); s3 = __shfl(a01, srcB);
        t0 = __shfl(a10, srcA); t1 = __shfl(a11, srcA);
        t2 = __shfl(a10, srcB); t3 = __shfl(a11, srcB);
        ap0 = fragw(act ? s0 : t0, act ? s1 : t1, act ? s2 : t2, act ? s3 : t3);
        s0 = __shfl(b00, srcA); s1 = __shfl(b01, srcA);
        s2 = __shfl(b00, srcB); s3 = __shfl(b01, srcB);
        t0 = __shfl(b10, srcA); t1 = __shfl(b11, srcA);
        t2 = __shfl(b10, srcB); t3 = __shfl(b11, srcB);
        ap1 = fragw(act ? s0 : t0, act ? s1 : t1, act ? s2 : t2, act ? s3 : t3);
    }
    // ------ PT^T = T^T @ P^T: lane holds PT[16w+l15][db=lq*4+r] --------------
    // -> row-k fragments (pta); k>=16 garbage killed by W2t exact zeros.
    bf16x8 pta0, pta1;
    {
        f32x4 pt0 = MFMA16(ttf0, ap0, fzero);
        f32x4 pt1 = MFMA16(ttf1, ap1, fzero);
        unsigned a0 = packbf(pt0[0], pt0[1]), a1 = packbf(pt0[2], pt0[3]);
        unsigned b0 = packbf(pt1[0], pt1[1]), b1 = packbf(pt1[2], pt1[3]);
        pta0 = fragw(__shfl(a0, srcA), __shfl(a1, srcA),
                     __shfl(a0, srcB), __shfl(a1, srcB));
        pta1 = fragw(__shfl(b0, srcA), __shfl(b1, srcA),
                     __shfl(b0, srcB), __shfl(b1, srcB));
    }
    // ---------------- epilogue MFMAs: Y = PT@W2 + X@Wo (classic orient.) -----
    f32x4 y0[4], y1[4];
    {
        #pragma unroll
        for (int t = 0; t < 4; ++t) {
            bf16x8 b0  = ld8_128(Wot, 16*t + l15, lq*8);
            bf16x8 b1  = ld8_128(Wot, 16*t + l15, 32 + lq*8);
            bf16x8 w2b = ld8_64 (W2t, 16*t + l15, lq*8);
            y0[t] = MFMA16(xa00, b0, fzero);
            y0[t] = MFMA16(xa01, b1, y0[t]);
            y0[t] = MFMA16(pta0, w2b, y0[t]);
            y1[t] = MFMA16(xa10, b0, fzero);
            y1[t] = MFMA16(xa11, b1, y1[t]);
            y1[t] = MFMA16(pta1, w2b, y1[t]);
        }
    }
    __syncthreads();   // barrier 2: ALL waves' LDS reads done -> arena is dead.
    // ---------------- + bo; LayerNorm; LDS-transpose; coalesced NT store -----
    // ONE Ybuf [64][64] f32 (16384 B at lds+0), reused q=0 then q=1: rows are
    // wave-private, so the write->read->write->read chain is same-wave FIFO.
    {
        float bo4[4], g4[4], b4[4];
        #pragma unroll
        for (int t = 0; t < 4; ++t) {
            int c = 16*t + l15;
            bo4[t] = bo[c]; g4[t] = lng[c]; b4[t] = lnb[c];
        }
        float* Ybuf = (float*)lds;
        #pragma unroll
        for (int q = 0; q < 2; ++q) {
            #pragma unroll
            for (int r = 0; r < 4; ++r) {
                float v0 = ((q == 0) ? y0[0][r] : y1[0][r]) + bo4[0];
                float v1 = ((q == 0) ? y0[1][r] : y1[1][r]) + bo4[1];
                float v2 = ((q == 0) ? y0[2][r] : y1[2][r]) + bo4[2];
                float v3 = ((q == 0) ? y0[3][r] : y1[3][r]) + bo4[3];
                float s1 = v0 + v1 + v2 + v3;
                float s2 = v0*v0 + v1*v1 + v2*v2 + v3*v3;
                #pragma unroll
                for (int off = 1; off < 16; off <<= 1) {
                    s1 += __shfl_xor(s1, off);
                    s2 += __shfl_xor(s2, off);
                }
                float mu  = s1 * 0.015625f;
                float var = s2 * 0.015625f - mu * mu;
                float rs  = rsqrtf(var + 1e-5f);
                float* yrow = Ybuf + (16*w + lq*4 + r) * 64;
                yrow[     l15] = (v0 - mu) * rs * g4[0] + b4[0];
                yrow[16 + l15] = (v1 - mu) * rs * g4[1] + b4[1];
                yrow[32 + l15] = (v2 - mu) * rs * g4[2] + b4[2];
                yrow[48 + l15] = (v3 - mu) * rs * g4[3] + b4[3];
            }
            // read back row-major; 4 fully-contiguous 1 KB wave NT stores
            float* gout = out + (size_t)(bn0 + q) * 4096;
            #pragma unroll
            for (int s = 0; s < 4; ++s) {
                int row = 16*w + 4*s + (l >> 4);
                f32x4 v = *(const f32x4*)(Ybuf + row*64 + (l & 15)*4);
                __builtin_nontemporal_store(v, (f32x4*)(gout + row*64 + (l & 15)*4));
            }
        }
    }
    #undef XBQ
}

extern "C" void kernel_launch(void* const* d_in, const int* in_sizes, int n_in,
                              void* d_out, int out_size, void* d_ws, size_t ws_size,
                              hipStream_t stream) {
    const float* voxel = (const float*)d_in[0];
    const float* trans = (const float*)d_in[1];
    const float* Wq = (const float*)d_in[2];
    const float* Wk = (const float*)d_in[3];
    const float* Wv = (const float*)d_in[4];
    const float* Wo = (const float*)d_in[5];
    const float* bo = (const float*)d_in[6];
    const float* g  = (const float*)d_in[7];
    const float* b  = (const float*)d_in[8];
    float* o = (float*)d_out;

    prep_weights<<<dim3(28), dim3(256), 0, stream>>>(Wq, Wk, Wv, Wo, (__bf16*)d_ws);
    xattn_kernel<<<dim3(GRID), dim3(256), 0, stream>>>(
        voxel, trans, (const float*)d_ws, bo, g, b, o);
}